// Round 2
// baseline (775.410 us; speedup 1.0000x reference)
//
#include <hip/hip_runtime.h>

// NuclearLossFunc: loss = sum(x^2) / (B*C), B*C = 2048.
//
// v3: DISAMBIGUATION BUILD (deliberate, temporary):
// nl_partial is launched TWICE (idempotent: second launch overwrites
// partial[] with identical values; nl_final sums once -> result exact).
// Purpose: dur_us(v3) - dur_us(v2) == true in-graph duration of one
// nl_partial, which is invisible in the top-5 rocprof table (all top
// slots are the harness's 2.147 GB workspace-poison fills at ~335 us).
//   - if delta ~ +88 us  -> kernel is at HBM roofline (Model A)
//   - if delta ~ +330 us -> kernel at ~1.6 TB/s, 4x headroom (Model B),
//     and the two nl_partial instances will surface in top-5 WITH
//     counters (hbm_gbps / VALUBusy / Occupancy) to diagnose why.

__global__ __launch_bounds__(256) void nl_partial(
    const float4* __restrict__ in, float* __restrict__ partial, long long n4)
{
    long long idx    = (long long)blockIdx.x * blockDim.x + threadIdx.x;
    long long stride = (long long)gridDim.x * blockDim.x;

    float a0 = 0.f, a1 = 0.f, a2 = 0.f, a3 = 0.f;
    long long i = idx;
    for (; i + 3 * stride < n4; i += 4 * stride) {
        float4 v0 = in[i];
        float4 v1 = in[i + stride];
        float4 v2 = in[i + 2 * stride];
        float4 v3 = in[i + 3 * stride];
        a0 += v0.x * v0.x + v0.y * v0.y + v0.z * v0.z + v0.w * v0.w;
        a1 += v1.x * v1.x + v1.y * v1.y + v1.z * v1.z + v1.w * v1.w;
        a2 += v2.x * v2.x + v2.y * v2.y + v2.z * v2.z + v2.w * v2.w;
        a3 += v3.x * v3.x + v3.y * v3.y + v3.z * v3.z + v3.w * v3.w;
    }
    for (; i < n4; i += stride) {
        float4 v = in[i];
        a0 += v.x * v.x + v.y * v.y + v.z * v.z + v.w * v.w;
    }
    float acc = (a0 + a1) + (a2 + a3);

    #pragma unroll
    for (int off = 32; off > 0; off >>= 1)
        acc += __shfl_down(acc, off, 64);

    __shared__ float smem[4];
    int lane = threadIdx.x & 63;
    int wave = threadIdx.x >> 6;
    if (lane == 0) smem[wave] = acc;
    __syncthreads();

    if (threadIdx.x == 0)
        partial[blockIdx.x] = smem[0] + smem[1] + smem[2] + smem[3];
}

__global__ __launch_bounds__(256) void nl_final(
    const float* __restrict__ partial, float* __restrict__ out,
    int nparts, float scale)
{
    float acc = 0.f;
    for (int i = threadIdx.x; i < nparts; i += 256)
        acc += partial[i];

    #pragma unroll
    for (int off = 32; off > 0; off >>= 1)
        acc += __shfl_down(acc, off, 64);

    __shared__ float smem[4];
    int lane = threadIdx.x & 63;
    int wave = threadIdx.x >> 6;
    if (lane == 0) smem[wave] = acc;
    __syncthreads();

    if (threadIdx.x == 0)
        out[0] = (smem[0] + smem[1] + smem[2] + smem[3]) * scale;
}

extern "C" void kernel_launch(void* const* d_in, const int* in_sizes, int n_in,
                              void* d_out, int out_size, void* d_ws, size_t ws_size,
                              hipStream_t stream) {
    const float* in = (const float*)d_in[0];
    float* out = (float*)d_out;
    float* partial = (float*)d_ws;  // 2048 floats = 8 KiB

    long long n  = (long long)in_sizes[0];   // 134217728
    long long n4 = n / 4;
    const float scale = 1.0f / 2048.0f;

    const int block = 256;
    const int grid  = 2048;

    // Launched twice ON PURPOSE (see header comment). Idempotent.
    nl_partial<<<grid, block, 0, stream>>>((const float4*)in, partial, n4);
    nl_partial<<<grid, block, 0, stream>>>((const float4*)in, partial, n4);
    nl_final<<<1, block, 0, stream>>>(partial, out, grid, scale);
}

// Round 4
// 649.937 us; speedup vs baseline: 1.1931x; 1.1931x over previous
//
#include <hip/hip_runtime.h>

// NuclearLossFunc: loss = sum(x^2) / (B*C), B*C = 2048.
// Pure HBM-streaming reduction over 512 MiB fp32.
//
// v5 = v4 with the nontemporal-load type fixed: clang's
// __builtin_nontemporal_load needs a native vector type, not
// HIP_vector_type<float,4>. Use ext_vector_type(4) float.
//
// Measured context (v3 probe): one nl_partial ~= 97 us ~= 90-95% of the
// 6.3 TB/s achievable HBM ceiling (512 MiB / 6.3 TB/s = 85 us floor).
// The other ~580 us of dur_us is the harness's 2.147 GB workspace-poison
// fills inside the timed region — not controllable here.

typedef float floatx4 __attribute__((ext_vector_type(4)));

__global__ __launch_bounds__(256) void nl_partial(
    const floatx4* __restrict__ in, float* __restrict__ partial, long long n4)
{
    long long idx    = (long long)blockIdx.x * blockDim.x + threadIdx.x;
    long long stride = (long long)gridDim.x * blockDim.x;

    float a0 = 0.f, a1 = 0.f, a2 = 0.f, a3 = 0.f;
    long long i = idx;
    // 4 independent load streams + accumulator chains per thread.
    for (; i + 3 * stride < n4; i += 4 * stride) {
        floatx4 v0 = __builtin_nontemporal_load(&in[i]);
        floatx4 v1 = __builtin_nontemporal_load(&in[i + stride]);
        floatx4 v2 = __builtin_nontemporal_load(&in[i + 2 * stride]);
        floatx4 v3 = __builtin_nontemporal_load(&in[i + 3 * stride]);
        a0 += v0.x * v0.x + v0.y * v0.y + v0.z * v0.z + v0.w * v0.w;
        a1 += v1.x * v1.x + v1.y * v1.y + v1.z * v1.z + v1.w * v1.w;
        a2 += v2.x * v2.x + v2.y * v2.y + v2.z * v2.z + v2.w * v2.w;
        a3 += v3.x * v3.x + v3.y * v3.y + v3.z * v3.z + v3.w * v3.w;
    }
    for (; i < n4; i += stride) {  // tail (empty for this shape)
        floatx4 v = __builtin_nontemporal_load(&in[i]);
        a0 += v.x * v.x + v.y * v.y + v.z * v.z + v.w * v.w;
    }
    float acc = (a0 + a1) + (a2 + a3);

    // wave-64 butterfly
    #pragma unroll
    for (int off = 32; off > 0; off >>= 1)
        acc += __shfl_down(acc, off, 64);

    __shared__ float smem[4];
    int lane = threadIdx.x & 63;
    int wave = threadIdx.x >> 6;
    if (lane == 0) smem[wave] = acc;
    __syncthreads();

    if (threadIdx.x == 0)
        partial[blockIdx.x] = smem[0] + smem[1] + smem[2] + smem[3];
}

__global__ __launch_bounds__(256) void nl_final(
    const float* __restrict__ partial, float* __restrict__ out,
    int nparts, float scale)
{
    float acc = 0.f;
    for (int i = threadIdx.x; i < nparts; i += 256)
        acc += partial[i];

    #pragma unroll
    for (int off = 32; off > 0; off >>= 1)
        acc += __shfl_down(acc, off, 64);

    __shared__ float smem[4];
    int lane = threadIdx.x & 63;
    int wave = threadIdx.x >> 6;
    if (lane == 0) smem[wave] = acc;
    __syncthreads();

    if (threadIdx.x == 0)
        out[0] = (smem[0] + smem[1] + smem[2] + smem[3]) * scale;
}

extern "C" void kernel_launch(void* const* d_in, const int* in_sizes, int n_in,
                              void* d_out, int out_size, void* d_ws, size_t ws_size,
                              hipStream_t stream) {
    const float* in = (const float*)d_in[0];
    float* out = (float*)d_out;
    float* partial = (float*)d_ws;  // 2048 floats = 8 KiB

    long long n  = (long long)in_sizes[0];   // 32*64*256*256 = 134217728
    long long n4 = n / 4;
    const float scale = 1.0f / 2048.0f;      // 1/(B*C)

    const int block = 256;
    const int grid  = 2048;  // 8 blocks/CU, 32 waves/CU = full occupancy

    nl_partial<<<grid, block, 0, stream>>>((const floatx4*)in, partial, n4);
    nl_final<<<1, block, 0, stream>>>(partial, out, grid, scale);
}